// Round 17
// baseline (986.125 us; speedup 1.0000x reference)
//
#include <hip/hip_runtime.h>
#include <hip/hip_bf16.h>

// QuantizedLinear: out[8192,11008] = x[8192,4096] @ dequant(W)^T
// Round 17: 2-blocks/CU with the occupancy arithmetic finally closed:
// per-SIMD reg file = 512 wave-regs UNIFIED (arch+acc). 2 blocks of 8 waves
// => 4 waves/SIMD => <=128 unified/wave => acc<=64 => 64x64 wave tile.
// Tile 128x256 (BK=32, LDS 48KiB) keeps intensity high (R15's 128x128 went
// HBM-bound). launch_bounds(512,4) caps ARCH at 64 (acc is AGPR, uncapped).

#define IN_F   4096
#define OUT_F  11008
#define M_DIM  8192
#define NGROUP 32

typedef __bf16 bf16x8 __attribute__((ext_vector_type(8)));
typedef float  f32x4  __attribute__((ext_vector_type(4)));
typedef unsigned short u16;
typedef u16 u16x8v __attribute__((ext_vector_type(8)));

__device__ __forceinline__ u16 f2bf(float f) {
  union { float f; unsigned u; } v; v.f = f;
  unsigned u = v.u;
  return (u16)((u + 0x7fffu + ((u >> 16) & 1u)) >> 16);  // RNE
}

__device__ __forceinline__ void gload_lds16(const void* gsrc, void* ldst) {
  __builtin_amdgcn_global_load_lds(
      (const __attribute__((address_space(1))) void*)gsrc,
      (__attribute__((address_space(3))) void*)ldst, 16, 0, 0);
}

// ---------------- dequant: packed 4-bit -> bf16 W[out][in] -----------------
__global__ __launch_bounds__(256) void dequant_w(const int* __restrict__ qw,
                                                 const int* __restrict__ qz,
                                                 const float* __restrict__ sc,
                                                 u16* __restrict__ W) {
  const int total = (IN_F / 2) * OUT_F / 4;  // int4 chunks
  int stride = gridDim.x * blockDim.x;
  for (int idx = blockIdx.x * blockDim.x + threadIdx.x; idx < total; idx += stride) {
    int j = idx << 2;
    int o = j >> 11;
    int g = (j >> 6) & 31;
    float z = (float)qz[(o << 5) + g];
    float s = sc[(o << 5) + g];
    int4 q = ((const int4*)qw)[idx];
    int qs0 = q.x, qs1 = q.y, qs2 = q.z, qs3 = q.w;
    u16x8v w;
    w[0] = f2bf(((float)(qs0 & 15) - z) * s);
    w[1] = f2bf(((float)((qs0 >> 4) & 15) - z) * s);
    w[2] = f2bf(((float)(qs1 & 15) - z) * s);
    w[3] = f2bf(((float)((qs1 >> 4) & 15) - z) * s);
    w[4] = f2bf(((float)(qs2 & 15) - z) * s);
    w[5] = f2bf(((float)((qs2 >> 4) & 15) - z) * s);
    w[6] = f2bf(((float)(qs3 & 15) - z) * s);
    w[7] = f2bf(((float)((qs3 >> 4) & 15) - z) * s);
    ((u16x8v*)W)[idx] = w;
  }
}

// ---------------- x fp32 -> bf16 -------------------------------------------
__global__ __launch_bounds__(256) void cvt_x(const float* __restrict__ x,
                                             u16* __restrict__ Xb) {
  const int total = M_DIM * IN_F / 8;
  int stride = gridDim.x * blockDim.x;
  for (int idx = blockIdx.x * blockDim.x + threadIdx.x; idx < total; idx += stride) {
    float4 a = ((const float4*)x)[idx * 2];
    float4 b = ((const float4*)x)[idx * 2 + 1];
    u16x8v v;
    v[0] = f2bf(a.x); v[1] = f2bf(a.y); v[2] = f2bf(a.z); v[3] = f2bf(a.w);
    v[4] = f2bf(b.x); v[5] = f2bf(b.y); v[6] = f2bf(b.z); v[7] = f2bf(b.w);
    ((u16x8v*)Xb)[idx] = v;
  }
}

// ---------------- 128x256 bf16 GEMM, BK=32, 2 blocks/CU: C = A * B^T -------
// 8 waves 2Mx4N; wave tile 64x64 (4x4 frags, acc = 64 AGPR). Per K-32 tile:
// {8 frag ds_reads cur buf; 3 stage-gloads t+1 -> other buf; LGKM0; 16 MFMA;
//  VMCNT0; BAR}. Waits hidden by the co-resident block (4 waves/SIMD).

#define BAR       __builtin_amdgcn_s_barrier()
#define SCHED0    __builtin_amdgcn_sched_barrier(0)
#define LGKM0     asm volatile("s_waitcnt lgkmcnt(0)" ::: "memory")
#define VMCNT0    asm volatile("s_waitcnt vmcnt(0)" ::: "memory")
#define PRIO(p)   __builtin_amdgcn_s_setprio(p)

__global__ __launch_bounds__(512, 4) void gemm128x256(const u16* __restrict__ A,
                                                      const u16* __restrict__ B,
                                                      float* __restrict__ C) {
  constexpr int K = IN_F, N = OUT_F;
  constexpr int NT = K / 32;  // 128 K-tiles
  __shared__ __align__(16) u16 sA[2][128 * 32];   // 8KB each
  __shared__ __align__(16) u16 sB[2][256 * 32];   // 16KB each; total 48KB

  const int NTN = OUT_F / 256;           // 43
  const int NWG = (M_DIM / 128) * NTN;   // 2752 (divisible by 8)
  int bid = blockIdx.x;
  int wg  = (bid & 7) * (NWG / 8) + (bid >> 3);  // bijective XCD swizzle
  int tm = wg / NTN, tn = wg - tm * NTN;
  int m0 = tm * 128, n0 = tn * 256;

  int tid  = threadIdx.x;
  int lane = tid & 63;
  int wave = tid >> 6;
  int wr = wave >> 2, wc = wave & 3;

  // staging: thread covers row (tid>>2), phys 16B slot tid&3.
  // phys slot s at row r holds logical slot s ^ ((r>>1)&3)  (involution).
  int rstage = tid >> 2;                               // 0..127
  int slot4  = tid & 3;
  int gslot  = ((slot4 ^ ((rstage >> 1) & 3)) << 3);   // global col elem
  int ldsoff = rstage * 32 + (slot4 << 3);             // linear LDS elem
  const u16* Ag = A + (size_t)(m0 + rstage) * K + gslot;
  const u16* Bg = B + (size_t)(n0 + rstage) * K + gslot;

  // per K-32 tile: A = 1 gload (128 rows), B = 2 gloads (256 rows).
  // (row+128)>>1 & 3 == row>>1 & 3, so gslot is valid for both B halves.
#define STAGE_AB(cb, kt) do {                                     \
    const u16* _ga = Ag + (kt) * 32;                              \
    const u16* _gb = Bg + (kt) * 32;                              \
    u16* _la = sA[cb] + ldsoff;                                   \
    u16* _lb = sB[cb] + ldsoff;                                   \
    gload_lds16(_ga, _la);                                        \
    gload_lds16(_gb, _lb);                                        \
    gload_lds16(_gb + (size_t)128 * K, _lb + 128 * 32);           \
  } while (0)

  // fragment reads: lane reads row base+(lane&15), k-quad q8=lane>>4 (0..3).
  // phys slot = q8 ^ (((lane&15)>>1)&3)   (row bases are multiples of 64)
  int q8 = lane >> 4;
  int fl = ((lane & 15) >> 1) & 3;
  int sl = ((q8 ^ fl) << 3);                     // elems
  int abase = (wr * 64 + (lane & 15)) * 32 + sl;
  int bbase = (wc * 64 + (lane & 15)) * 32 + sl;

  bf16x8 a_[4], b_[4];
  f32x4 acc[4][4] = {};

#define LDFRAGS(cb) do {                                          \
    const u16* _pa = sA[cb] + abase;                              \
    const u16* _pb = sB[cb] + bbase;                              \
    a_[0] = *(const bf16x8*)(_pa);                                \
    a_[1] = *(const bf16x8*)(_pa + 512);                          \
    a_[2] = *(const bf16x8*)(_pa + 1024);                         \
    a_[3] = *(const bf16x8*)(_pa + 1536);                         \
    b_[0] = *(const bf16x8*)(_pb);                                \
    b_[1] = *(const bf16x8*)(_pb + 512);                          \
    b_[2] = *(const bf16x8*)(_pb + 1024);                         \
    b_[3] = *(const bf16x8*)(_pb + 1536);                         \
  } while (0)

  // 16 MFMAs, all independent accumulators
#define MFMAS do {                                                             \
    _Pragma("unroll") for (int mf = 0; mf < 4; mf++)                           \
      _Pragma("unroll") for (int nf = 0; nf < 4; nf++)                         \
        acc[mf][nf] = __builtin_amdgcn_mfma_f32_16x16x32_bf16(                 \
            a_[mf], b_[nf], acc[mf][nf], 0, 0, 0);                             \
  } while (0)

#define TILE(c, t) do {                                           \
    LDFRAGS(c);                                                   \
    STAGE_AB((c) ^ 1, ((t) + 1) & (NT - 1));                      \
    LGKM0;                                                        \
    PRIO(1); MFMAS; PRIO(0);                                      \
    VMCNT0; BAR;                                                  \
  } while (0)

  // prologue: stage tile0 -> buf0, drain, barrier.
  STAGE_AB(0, 0);
  VMCNT0; BAR;
  SCHED0;
  asm volatile("" ::: "memory");

#pragma unroll 1
  for (int t = 0; t < NT; t += 2) {
    TILE(0, t);
    TILE(1, t + 1);
  }

  // C/D layout: col = lane&15, row = (lane>>4)*4 + j
  // out row = m0 + wr*64 + mf*16 + (lane>>4)*4 + j
  // out col = n0 + wc*64 + nf*16 + (lane&15)
  float* Cp = C + (size_t)(m0 + wr * 64 + ((lane >> 4) << 2)) * N
                + n0 + wc * 64 + (lane & 15);
#pragma unroll
  for (int mf = 0; mf < 4; mf++)
#pragma unroll
    for (int nf = 0; nf < 4; nf++)
#pragma unroll
      for (int j = 0; j < 4; j++)
        Cp[(size_t)(mf * 16 + j) * N + nf * 16] = acc[mf][nf][j];
}

// ---------------- exact fp32 fallback (only if ws too small) ---------------
__global__ __launch_bounds__(256) void naive_gemm(const float* __restrict__ x,
                                                  const int* __restrict__ qw,
                                                  const int* __restrict__ qz,
                                                  const float* __restrict__ sc,
                                                  float* __restrict__ out) {
  __shared__ float xs[IN_F];
  int m = blockIdx.y;
  int n = blockIdx.x * 256 + threadIdx.x;
  for (int i = threadIdx.x; i < IN_F; i += 256) xs[i] = x[(size_t)m * IN_F + i];
  __syncthreads();
  float acc = 0.f;
  const int* qrow = qw + (size_t)n * (IN_F / 2);
  for (int g = 0; g < NGROUP; g++) {
    float z = (float)qz[n * NGROUP + g];
    float s = sc[n * NGROUP + g];
    for (int t = 0; t < 64; t++) {
      int q = qrow[g * 64 + t];
      acc += xs[g * 128 + 2 * t] * ((float)(q & 15) - z) * s;
      acc += xs[g * 128 + 2 * t + 1] * ((float)((q >> 4) & 15) - z) * s;
    }
  }
  out[(size_t)m * OUT_F + n] = acc;
}

extern "C" void kernel_launch(void* const* d_in, const int* in_sizes, int n_in,
                              void* d_out, int out_size, void* d_ws, size_t ws_size,
                              hipStream_t stream) {
  const float* x  = (const float*)d_in[0];
  const int*   qw = (const int*)d_in[1];
  const int*   qz = (const int*)d_in[2];
  const float* sc = (const float*)d_in[3];
  float* out = (float*)d_out;

  const size_t WBYTES = (size_t)OUT_F * IN_F * 2;
  const size_t XBYTES = (size_t)M_DIM * IN_F * 2;

  if (ws_size >= WBYTES + XBYTES) {
    u16* Wb = (u16*)d_ws;
    u16* Xb = (u16*)((char*)d_ws + WBYTES);
    dequant_w<<<2048, 256, 0, stream>>>(qw, qz, sc, Wb);
    cvt_x<<<2048, 256, 0, stream>>>(x, Xb);
    gemm128x256<<<(M_DIM / 128) * (OUT_F / 256), 512, 0, stream>>>(Xb, Wb, out);
  } else {
    naive_gemm<<<dim3(OUT_F / 256, M_DIM), 256, 0, stream>>>(x, qw, qz, sc, out);
  }
}

// Round 18
// 804.031 us; speedup vs baseline: 1.2265x; 1.2265x over previous
//
#include <hip/hip_runtime.h>
#include <hip/hip_bf16.h>

// QuantizedLinear: out[8192,11008] = x[8192,4096] @ dequant(W)^T
// Round 18: R17 (2 blocks/CU, 128x256, BK=32) + memory-system fixes:
//  (1) triple-buffer LDS (72KB): stage t+2 during tile t, vmcnt(3) at tile
//      end -> issue->wait ~1.3 tiles > HBM latency;
//  (2) tm-major XCD chunking (tm_l=l&7, tn=l>>3): resident set 24MB/XCD;
//  (3) nontemporal C stores: stop evicting A/B panels from L3.

#define IN_F   4096
#define OUT_F  11008
#define M_DIM  8192
#define NGROUP 32

typedef __bf16 bf16x8 __attribute__((ext_vector_type(8)));
typedef float  f32x4  __attribute__((ext_vector_type(4)));
typedef unsigned short u16;
typedef u16 u16x8v __attribute__((ext_vector_type(8)));

__device__ __forceinline__ u16 f2bf(float f) {
  union { float f; unsigned u; } v; v.f = f;
  unsigned u = v.u;
  return (u16)((u + 0x7fffu + ((u >> 16) & 1u)) >> 16);  // RNE
}

__device__ __forceinline__ void gload_lds16(const void* gsrc, void* ldst) {
  __builtin_amdgcn_global_load_lds(
      (const __attribute__((address_space(1))) void*)gsrc,
      (__attribute__((address_space(3))) void*)ldst, 16, 0, 0);
}

// ---------------- dequant: packed 4-bit -> bf16 W[out][in] -----------------
__global__ __launch_bounds__(256) void dequant_w(const int* __restrict__ qw,
                                                 const int* __restrict__ qz,
                                                 const float* __restrict__ sc,
                                                 u16* __restrict__ W) {
  const int total = (IN_F / 2) * OUT_F / 4;  // int4 chunks
  int stride = gridDim.x * blockDim.x;
  for (int idx = blockIdx.x * blockDim.x + threadIdx.x; idx < total; idx += stride) {
    int j = idx << 2;
    int o = j >> 11;
    int g = (j >> 6) & 31;
    float z = (float)qz[(o << 5) + g];
    float s = sc[(o << 5) + g];
    int4 q = ((const int4*)qw)[idx];
    int qs0 = q.x, qs1 = q.y, qs2 = q.z, qs3 = q.w;
    u16x8v w;
    w[0] = f2bf(((float)(qs0 & 15) - z) * s);
    w[1] = f2bf(((float)((qs0 >> 4) & 15) - z) * s);
    w[2] = f2bf(((float)(qs1 & 15) - z) * s);
    w[3] = f2bf(((float)((qs1 >> 4) & 15) - z) * s);
    w[4] = f2bf(((float)(qs2 & 15) - z) * s);
    w[5] = f2bf(((float)((qs2 >> 4) & 15) - z) * s);
    w[6] = f2bf(((float)(qs3 & 15) - z) * s);
    w[7] = f2bf(((float)((qs3 >> 4) & 15) - z) * s);
    ((u16x8v*)W)[idx] = w;
  }
}

// ---------------- x fp32 -> bf16 -------------------------------------------
__global__ __launch_bounds__(256) void cvt_x(const float* __restrict__ x,
                                             u16* __restrict__ Xb) {
  const int total = M_DIM * IN_F / 8;
  int stride = gridDim.x * blockDim.x;
  for (int idx = blockIdx.x * blockDim.x + threadIdx.x; idx < total; idx += stride) {
    float4 a = ((const float4*)x)[idx * 2];
    float4 b = ((const float4*)x)[idx * 2 + 1];
    u16x8v v;
    v[0] = f2bf(a.x); v[1] = f2bf(a.y); v[2] = f2bf(a.z); v[3] = f2bf(a.w);
    v[4] = f2bf(b.x); v[5] = f2bf(b.y); v[6] = f2bf(b.z); v[7] = f2bf(b.w);
    ((u16x8v*)Xb)[idx] = v;
  }
}

// ---------------- 128x256 bf16 GEMM, BK=32, 3-buf, 2 blocks/CU -------------
// 8 waves 2Mx4N; wave tile 64x64 (acc = 64 AGPR). Per K-32 tile t:
// {8 frag ds_reads buf[t%3]; 3 stage-gloads (t+2) -> buf[(t+2)%3]; LGKM0;
//  16 MFMA; VMCNT3 (drains t+1's stages, leaves t+2's); BAR}.

#define BAR       __builtin_amdgcn_s_barrier()
#define SCHED0    __builtin_amdgcn_sched_barrier(0)
#define LGKM0     asm volatile("s_waitcnt lgkmcnt(0)" ::: "memory")
#define VMCNT3    asm volatile("s_waitcnt vmcnt(3)" ::: "memory")
#define PRIO(p)   __builtin_amdgcn_s_setprio(p)

__global__ __launch_bounds__(512, 4) void gemm128x256(const u16* __restrict__ A,
                                                      const u16* __restrict__ B,
                                                      float* __restrict__ C) {
  constexpr int K = IN_F, N = OUT_F;
  constexpr int NT = K / 32;  // 128 K-tiles
  __shared__ __align__(16) u16 sA[3][128 * 32];   // 8KB each
  __shared__ __align__(16) u16 sB[3][256 * 32];   // 16KB each; total 72KB

  const int NTN = OUT_F / 256;           // 43
  // tm-major XCD chunking: xcd = bid&7 owns tm in [8*xcd, 8*xcd+8);
  // within XCD, tm varies fastest -> 64 resident blocks share 8 A + 8 B panels.
  int bid = blockIdx.x;
  int xcd = bid & 7;
  int l   = bid >> 3;                 // 0..343 = 8 tm_l x 43 tn
  int tm_l = l & 7, tn = l >> 3;
  int tm = xcd * 8 + tm_l;
  int m0 = tm * 128, n0 = tn * 256;

  int tid  = threadIdx.x;
  int lane = tid & 63;
  int wave = tid >> 6;
  int wr = wave >> 2, wc = wave & 3;

  // staging: thread covers row (tid>>2), phys 16B slot tid&3.
  // phys slot s at row r holds logical slot s ^ ((r>>1)&3)  (involution).
  int rstage = tid >> 2;                               // 0..127
  int slot4  = tid & 3;
  int gslot  = ((slot4 ^ ((rstage >> 1) & 3)) << 3);   // global col elem
  int ldsoff = rstage * 32 + (slot4 << 3);             // linear LDS elem
  const u16* Ag = A + (size_t)(m0 + rstage) * K + gslot;
  const u16* Bg = B + (size_t)(n0 + rstage) * K + gslot;

  // per K-32 tile: A = 1 gload (128 rows), B = 2 gloads (256 rows).
  // (row+128)>>1 & 3 == row>>1 & 3, so gslot is valid for both B halves.
#define STAGE_AB(cb, kt) do {                                     \
    const u16* _ga = Ag + (kt) * 32;                              \
    const u16* _gb = Bg + (kt) * 32;                              \
    u16* _la = sA[cb] + ldsoff;                                   \
    u16* _lb = sB[cb] + ldsoff;                                   \
    gload_lds16(_ga, _la);                                        \
    gload_lds16(_gb, _lb);                                        \
    gload_lds16(_gb + (size_t)128 * K, _lb + 128 * 32);           \
  } while (0)

  // fragment reads: lane reads row base+(lane&15), k-quad q8=lane>>4 (0..3).
  // phys slot = q8 ^ (((lane&15)>>1)&3)   (row bases are multiples of 64)
  int q8 = lane >> 4;
  int fl = ((lane & 15) >> 1) & 3;
  int sl = ((q8 ^ fl) << 3);                     // elems
  int abase = (wr * 64 + (lane & 15)) * 32 + sl;
  int bbase = (wc * 64 + (lane & 15)) * 32 + sl;

  bf16x8 a_[4], b_[4];
  f32x4 acc[4][4] = {};

#define LDFRAGS(cb) do {                                          \
    const u16* _pa = sA[cb] + abase;                              \
    const u16* _pb = sB[cb] + bbase;                              \
    a_[0] = *(const bf16x8*)(_pa);                                \
    a_[1] = *(const bf16x8*)(_pa + 512);                          \
    a_[2] = *(const bf16x8*)(_pa + 1024);                         \
    a_[3] = *(const bf16x8*)(_pa + 1536);                         \
    b_[0] = *(const bf16x8*)(_pb);                                \
    b_[1] = *(const bf16x8*)(_pb + 512);                          \
    b_[2] = *(const bf16x8*)(_pb + 1024);                         \
    b_[3] = *(const bf16x8*)(_pb + 1536);                         \
  } while (0)

  // 16 MFMAs, all independent accumulators
#define MFMAS do {                                                             \
    _Pragma("unroll") for (int mf = 0; mf < 4; mf++)                           \
      _Pragma("unroll") for (int nf = 0; nf < 4; nf++)                         \
        acc[mf][nf] = __builtin_amdgcn_mfma_f32_16x16x32_bf16(                 \
            a_[mf], b_[nf], acc[mf][nf], 0, 0, 0);                             \
  } while (0)

  // cr = t%3 (read buf), cs = (t+2)%3 (stage buf)
#define TILE(cr, cs, t) do {                                      \
    LDFRAGS(cr);                                                  \
    STAGE_AB(cs, ((t) + 2) & (NT - 1));                           \
    LGKM0;                                                        \
    PRIO(1); MFMAS; PRIO(0);                                      \
    VMCNT3; BAR;                                                  \
  } while (0)

  // prologue: stage t0->buf0, t1->buf1; vmcnt(3) drains t0's 3 (leaves t1's
  // 3 in flight = steady-state invariant); BAR.
  STAGE_AB(0, 0);
  STAGE_AB(1, 1);
  VMCNT3; BAR;
  SCHED0;
  asm volatile("" ::: "memory");

#pragma unroll 1
  for (int t = 0; t < NT - 2; t += 3) {
    TILE(0, 2, t);
    TILE(1, 0, t + 1);
    TILE(2, 1, t + 2);
  }
  TILE(0, 2, NT - 2);   // t=126: reads buf0; stage wraps to tile 0 (harmless)
  TILE(1, 0, NT - 1);   // t=127: reads buf1; stage wraps to tile 1 (harmless)

  // C/D layout: col = lane&15, row = (lane>>4)*4 + j.  Nontemporal stores:
  // C is write-once; keep A/B panels resident in L3.
  float* Cp = C + (size_t)(m0 + wr * 64 + ((lane >> 4) << 2)) * N
                + n0 + wc * 64 + (lane & 15);
#pragma unroll
  for (int mf = 0; mf < 4; mf++)
#pragma unroll
    for (int nf = 0; nf < 4; nf++)
#pragma unroll
      for (int j = 0; j < 4; j++)
        __builtin_nontemporal_store(acc[mf][nf][j],
                                    &Cp[(size_t)(mf * 16 + j) * N + nf * 16]);
}

// ---------------- exact fp32 fallback (only if ws too small) ---------------
__global__ __launch_bounds__(256) void naive_gemm(const float* __restrict__ x,
                                                  const int* __restrict__ qw,
                                                  const int* __restrict__ qz,
                                                  const float* __restrict__ sc,
                                                  float* __restrict__ out) {
  __shared__ float xs[IN_F];
  int m = blockIdx.y;
  int n = blockIdx.x * 256 + threadIdx.x;
  for (int i = threadIdx.x; i < IN_F; i += 256) xs[i] = x[(size_t)m * IN_F + i];
  __syncthreads();
  float acc = 0.f;
  const int* qrow = qw + (size_t)n * (IN_F / 2);
  for (int g = 0; g < NGROUP; g++) {
    float z = (float)qz[n * NGROUP + g];
    float s = sc[n * NGROUP + g];
    for (int t = 0; t < 64; t++) {
      int q = qrow[g * 64 + t];
      acc += xs[g * 128 + 2 * t] * ((float)(q & 15) - z) * s;
      acc += xs[g * 128 + 2 * t + 1] * ((float)((q >> 4) & 15) - z) * s;
    }
  }
  out[(size_t)m * OUT_F + n] = acc;
}

extern "C" void kernel_launch(void* const* d_in, const int* in_sizes, int n_in,
                              void* d_out, int out_size, void* d_ws, size_t ws_size,
                              hipStream_t stream) {
  const float* x  = (const float*)d_in[0];
  const int*   qw = (const int*)d_in[1];
  const int*   qz = (const int*)d_in[2];
  const float* sc = (const float*)d_in[3];
  float* out = (float*)d_out;

  const size_t WBYTES = (size_t)OUT_F * IN_F * 2;
  const size_t XBYTES = (size_t)M_DIM * IN_F * 2;

  if (ws_size >= WBYTES + XBYTES) {
    u16* Wb = (u16*)d_ws;
    u16* Xb = (u16*)((char*)d_ws + WBYTES);
    dequant_w<<<2048, 256, 0, stream>>>(qw, qz, sc, Wb);
    cvt_x<<<2048, 256, 0, stream>>>(x, Xb);
    gemm128x256<<<(M_DIM / 128) * (OUT_F / 256), 512, 0, stream>>>(Xb, Wb, out);
  } else {
    naive_gemm<<<dim3(OUT_F / 256, M_DIM), 256, 0, stream>>>(x, qw, qz, sc, out);
  }
}